// Round 1
// baseline (108751.892 us; speedup 1.0000x reference)
//
#include <hip/hip_runtime.h>

#define NWG     256
#define TPB     256
#define T_STEPS 1024
#define HD      1024
#define DIN     256
#define K0      1280        // DIN + HD  (layer 0 concat [x_t ; h0])
#define K1      2048        // HD + HD   (layer 1 concat [y0_t ; h1])
#define K0P     1288        // padded LDS row stride (shorts) -> 2-way-free banks
#define K1P     2056
#define SMEM_SHORTS (16*K0P + 16*K1P)
#define SMEM_BYTES  (SMEM_SHORTS*2)   // 107,008 B

// workspace layout (bytes)
#define WS_BAR  0
#define WS_H0   4096
#define WS_H1   (4096 + 262144)
#define WS_ZERO (4096 + 2*262144)     // memset range [0, WS_ZERO)
#define WS_X8   1048576               // 1024*32*64*8 bf16 = 33.5 MB
#define H0_INT4_PER_BUF   8192        // 128 planes * 64 batch
#define H0_USHORT_PER_BUF 65536

typedef float  f32x4  __attribute__((ext_vector_type(4)));
typedef __bf16 bf16x8 __attribute__((ext_vector_type(8)));

__device__ __forceinline__ short f2bf(float f){
  union { float f; unsigned u; } a; a.f = f;
  unsigned u = a.u;
  u += 0x7fffu + ((u >> 16) & 1u);   // RNE
  return (short)(u >> 16);
}
__device__ __forceinline__ float sigmf(float x){ return 1.0f/(1.0f + __expf(-x)); }
__device__ __forceinline__ float tanhf_fast(float x){ return 2.0f*sigmf(2.0f*x) - 1.0f; }

// x [B,T,D] fp32 -> X8 bf16 in [T][D/8][B][8] (int4 = one B-fragment slice)
__global__ void xpose_kernel(const float* __restrict__ x, short* __restrict__ X8){
  int idx   = blockIdx.x*256 + threadIdx.x;     // 0 .. 2,097,151
  int t     = idx >> 11;
  int rem   = idx & 2047;
  int plane = rem >> 6;                          // 0..31
  int b     = rem & 63;
  const float* src = x + ((size_t)b << 18) + (t << 8) + (plane << 3);
  short tmp[8];
  #pragma unroll
  for (int j = 0; j < 8; ++j) tmp[j] = f2bf(src[j]);
  int4 v; __builtin_memcpy(&v, tmp, 16);
  ((int4*)X8)[idx] = v;
}

__device__ __forceinline__ void gridbar(unsigned* cnt, unsigned* gen, unsigned epoch){
  __threadfence();               // release: flush my h-writes device-wide
  __syncthreads();
  if (threadIdx.x == 0){
    unsigned a = __hip_atomic_fetch_add(cnt, 1u, __ATOMIC_ACQ_REL, __HIP_MEMORY_SCOPE_AGENT);
    if (a == epoch*NWG - 1u){
      __hip_atomic_store(gen, epoch, __ATOMIC_RELEASE, __HIP_MEMORY_SCOPE_AGENT);
    } else {
      while (__hip_atomic_load(gen, __ATOMIC_RELAXED, __HIP_MEMORY_SCOPE_AGENT) < epoch)
        __builtin_amdgcn_s_sleep(2);
    }
  }
  __syncthreads();
  __threadfence();               // acquire: invalidate stale L1/L2 lines
}

extern "C" __global__ void __launch_bounds__(TPB, 1)
lstm_mega(const float* __restrict__ Wih0, const float* __restrict__ Whh0,
          const float* __restrict__ bih0, const float* __restrict__ bhh0,
          const float* __restrict__ Wih1, const float* __restrict__ Whh1,
          const float* __restrict__ bih1, const float* __restrict__ bhh1,
          const short* __restrict__ X8, unsigned* bar,
          short* __restrict__ H0, short* __restrict__ H1,
          float* __restrict__ out)
{
  extern __shared__ short smem[];
  short* W0s = smem;             // [16][K0P]
  short* W1s = smem + 16*K0P;    // [16][K1P]
  const int tid = threadIdx.x;
  const int wg  = blockIdx.x;

  // Stage this WG's 16 gate-rows of both layers into LDS (bf16).
  // LDS row m <-> (col_offset = m>>2, gate = m&3); global gate-row = gate*HD + wg*4 + col_offset
  for (int m = 0; m < 16; ++m){
    int gr = (m & 3)*HD + wg*4 + (m >> 2);
    const float* wih0r = Wih0 + (size_t)gr*DIN;
    const float* whh0r = Whh0 + (size_t)gr*HD;
    for (int k = tid; k < K0; k += TPB)
      W0s[m*K0P + k] = f2bf(k < DIN ? wih0r[k] : whh0r[k - DIN]);
    const float* wih1r = Wih1 + (size_t)gr*HD;
    const float* whh1r = Whh1 + (size_t)gr*HD;
    for (int k = tid; k < K1; k += TPB)
      W1s[m*K1P + k] = f2bf(k < HD ? wih1r[k] : whh1r[k - HD]);
  }
  __syncthreads();

  const int lane  = tid & 63;
  const int wv    = tid >> 6;       // wave 0..3 -> batches 16wv..16wv+15
  const int q     = lane >> 4;      // k-quad for frags; col-offset for C/D
  const int nn    = lane & 15;      // batch-sub for B-frag & C/D; A-row for A-frag
  const int batch = wv*16 + nn;
  const int col   = wg*4 + q;

  float bias0[4], bias1[4];
  #pragma unroll
  for (int r = 0; r < 4; ++r){
    bias0[r] = bih0[r*HD + col] + bhh0[r*HD + col];
    bias1[r] = bih1[r*HD + col] + bhh1[r*HD + col];
  }

  const int4* X4  = (const int4*)X8;
  const int4* H0r = (const int4*)H0;
  const int4* H1r = (const int4*)H1;
  unsigned short* H0w = (unsigned short*)H0;
  unsigned short* H1w = (unsigned short*)H1;

  unsigned* cnt = bar;
  unsigned* gen = bar + 16;        // 64B apart
  unsigned ep = 0;

  float c0 = 0.f, c1 = 0.f, h0v = 0.f, h1v = 0.f;
  const int hwofs = (col >> 3)*512 + (col & 7);   // ushort offset sans batch/buf

  for (int t = 0; t < T_STEPS; ++t){
    const int cur = t & 1, nxt = cur ^ 1;

    // ---------- layer 0: gates = W0 @ [x_t ; h0_{t-1}] ----------
    f32x4 acc[4] = {{0,0,0,0},{0,0,0,0},{0,0,0,0},{0,0,0,0}};
    {
      const int4* xb = X4  + t*2048;
      const int4* hb = H0r + cur*H0_INT4_PER_BUF;
      #pragma unroll 8
      for (int kb = 0; kb < 40; ++kb){
        bf16x8 a, b;
        __builtin_memcpy(&a, &W0s[nn*K0P + kb*32 + q*8], 16);
        int4 braw = (kb < 8) ? xb[(kb*4 + q)*64 + batch]
                             : hb[((kb - 8)*4 + q)*64 + batch];
        __builtin_memcpy(&b, &braw, 16);
        acc[kb & 3] = __builtin_amdgcn_mfma_f32_16x16x32_bf16(a, b, acc[kb & 3], 0, 0, 0);
      }
    }
    {
      f32x4 s = (acc[0] + acc[1]) + (acc[2] + acc[3]);
      float ii = sigmf(s[0] + bias0[0]);
      float ff = sigmf(s[1] + bias0[1]);
      float gg = tanhf_fast(s[2] + bias0[2]);
      float oo = sigmf(s[3] + bias0[3]);
      c0  = ff*c0 + ii*gg;
      h0v = oo*tanhf_fast(c0);
      H0w[nxt*H0_USHORT_PER_BUF + hwofs + batch*8] = (unsigned short)f2bf(h0v);
    }
    ++ep; gridbar(cnt, gen, ep);

    // ---------- layer 1: gates = W1 @ [y0_t ; h1_{t-1}] ----------
    acc[0] = (f32x4){0,0,0,0}; acc[1] = (f32x4){0,0,0,0};
    acc[2] = (f32x4){0,0,0,0}; acc[3] = (f32x4){0,0,0,0};
    {
      const int4* yb = H0r + nxt*H0_INT4_PER_BUF;   // y0_t just produced
      const int4* hb = H1r + cur*H0_INT4_PER_BUF;
      #pragma unroll 8
      for (int kb = 0; kb < 64; ++kb){
        bf16x8 a, b;
        __builtin_memcpy(&a, &W1s[nn*K1P + kb*32 + q*8], 16);
        int4 braw = (kb < 32) ? yb[(kb*4 + q)*64 + batch]
                              : hb[((kb - 32)*4 + q)*64 + batch];
        __builtin_memcpy(&b, &braw, 16);
        acc[kb & 3] = __builtin_amdgcn_mfma_f32_16x16x32_bf16(a, b, acc[kb & 3], 0, 0, 0);
      }
    }
    {
      f32x4 s = (acc[0] + acc[1]) + (acc[2] + acc[3]);
      float ii = sigmf(s[0] + bias1[0]);
      float ff = sigmf(s[1] + bias1[1]);
      float gg = tanhf_fast(s[2] + bias1[2]);
      float oo = sigmf(s[3] + bias1[3]);
      c1  = ff*c1 + ii*gg;
      h1v = oo*tanhf_fast(c1);
      H1w[nxt*H0_USHORT_PER_BUF + hwofs + batch*8] = (unsigned short)f2bf(h1v);
    }
    ++ep; gridbar(cnt, gen, ep);
  }

  // out = [h0; h1; c0; c1] each [B,H] fp32
  out[          batch*HD + col] = h0v;
  out[ 65536 +  batch*HD + col] = h1v;
  out[131072 +  batch*HD + col] = c0;
  out[196608 +  batch*HD + col] = c1;
}

extern "C" void kernel_launch(void* const* d_in, const int* in_sizes, int n_in,
                              void* d_out, int out_size, void* d_ws, size_t ws_size,
                              hipStream_t stream)
{
  const float* x    = (const float*)d_in[0];
  const float* Wih0 = (const float*)d_in[1];
  const float* Whh0 = (const float*)d_in[2];
  const float* bih0 = (const float*)d_in[3];
  const float* bhh0 = (const float*)d_in[4];
  const float* Wih1 = (const float*)d_in[5];
  const float* Whh1 = (const float*)d_in[6];
  const float* bih1 = (const float*)d_in[7];
  const float* bhh1 = (const float*)d_in[8];
  float* out = (float*)d_out;

  char* ws = (char*)d_ws;
  unsigned* bar = (unsigned*)(ws + WS_BAR);
  short* H0 = (short*)(ws + WS_H0);
  short* H1 = (short*)(ws + WS_H1);
  short* X8 = (short*)(ws + WS_X8);

  // zero barrier counters + both state double-buffers (h=0 initial state)
  hipMemsetAsync(d_ws, 0, WS_ZERO, stream);
  xpose_kernel<<<8192, 256, 0, stream>>>(x, X8);

  hipFuncSetAttribute((const void*)lstm_mega,
                      hipFuncAttributeMaxDynamicSharedMemorySize, SMEM_BYTES);

  void* args[] = {(void*)&Wih0,(void*)&Whh0,(void*)&bih0,(void*)&bhh0,
                  (void*)&Wih1,(void*)&Whh1,(void*)&bih1,(void*)&bhh1,
                  (void*)&X8,(void*)&bar,(void*)&H0,(void*)&H1,(void*)&out};
  hipLaunchCooperativeKernel((void*)lstm_mega, dim3(NWG), dim3(TPB),
                             args, SMEM_BYTES, stream);
}

// Round 2
// 12694.427 us; speedup vs baseline: 8.5669x; 8.5669x over previous
//
#include <hip/hip_runtime.h>

#define NWG     256
#define TPB     256
#define NL0     128          // WGs [0,128) = layer0, [128,256) = layer1
#define T_STEPS 1024
#define HD      1024
#define DIN     256
#define K0      1280         // DIN + HD
#define K1      2048         // HD + HD
#define K0P     1288         // padded LDS row stride (shorts), 16B-aligned rows
#define K1P     2056
#define SMEM_BYTES (32*K1P*2)   // 131,584 B (layer1 worst case)

// workspace layout (bytes)
#define WS_FLAGS 0                       // 256 x 64B
#define WS_GEN   16384                   // 16 x 64B
#define WS_H0    32768                   // 2 x 131072
#define WS_H1    (32768 + 262144)
#define WS_ZERO  (32768 + 524288)        // memset [0, WS_ZERO)
#define WS_X8    1048576                 // 1024*32*64*8 bf16 = 33.5 MB
#define HBUF_US  65536                   // ushorts per h buffer
#define HBUF_U64 16384                   // u64 per h buffer
#define NGEN     16

typedef float  f32x4  __attribute__((ext_vector_type(4)));
typedef __bf16 bf16x8 __attribute__((ext_vector_type(8)));

__device__ __forceinline__ unsigned short f2bf(float f){
  union { float f; unsigned u; } a; a.f = f;
  unsigned u = a.u;
  u += 0x7fffu + ((u >> 16) & 1u);   // RNE
  return (unsigned short)(u >> 16);
}
__device__ __forceinline__ float sigmf(float x){ return 1.0f/(1.0f + __expf(-x)); }
__device__ __forceinline__ float tanhf_fast(float x){ return 2.0f*sigmf(2.0f*x) - 1.0f; }

// coherent (IF-level, cross-XCD) accessors — per-access sc0 sc1, no L2 invalidation
__device__ __forceinline__ unsigned long long ld64c(const unsigned long long* p){
  return __hip_atomic_load(p, __ATOMIC_RELAXED, __HIP_MEMORY_SCOPE_AGENT);
}
__device__ __forceinline__ void st16c(unsigned short* p, unsigned short v){
  __hip_atomic_store(p, v, __ATOMIC_RELAXED, __HIP_MEMORY_SCOPE_AGENT);
}
__device__ __forceinline__ unsigned ldflag(const unsigned* p){
  return __hip_atomic_load(p, __ATOMIC_RELAXED, __HIP_MEMORY_SCOPE_AGENT);
}
__device__ __forceinline__ void stflag(unsigned* p, unsigned v){
  __hip_atomic_store(p, v, __ATOMIC_RELAXED, __HIP_MEMORY_SCOPE_AGENT);
}

// flag-tree grid barrier: no RMW, no threadfence, no L2 invalidate.
__device__ __forceinline__ void gridbar(unsigned* flags, unsigned* gen,
                                        unsigned ep, int wg, int tid){
  asm volatile("s_waitcnt vmcnt(0)" ::: "memory");  // my h-stores (sc1 write-through) are at IF
  __syncthreads();                                  // all waves of this WG drained
  if (wg == 0){
    if (tid > 0){
      while (ldflag(&flags[tid*16]) < ep) __builtin_amdgcn_s_sleep(4);
    }
    __syncthreads();
    if (tid < NGEN) stflag(&gen[tid*16], ep);
    __syncthreads();
  } else {
    if (tid == 0){
      stflag(&flags[wg*16], ep);
      while (ldflag(&gen[(wg & (NGEN-1))*16]) < ep) __builtin_amdgcn_s_sleep(4);
    }
    __syncthreads();
  }
}

// x [B,T,D] fp32 -> X8 bf16 in [T][D/8][B][8]
__global__ void xpose_kernel(const float* __restrict__ x, unsigned short* __restrict__ X8){
  int idx   = blockIdx.x*256 + threadIdx.x;
  int t     = idx >> 11;
  int rem   = idx & 2047;
  int plane = rem >> 6;
  int b     = rem & 63;
  const float* src = x + ((size_t)b << 18) + (t << 8) + (plane << 3);
  unsigned short tmp[8];
  #pragma unroll
  for (int j = 0; j < 8; ++j) tmp[j] = f2bf(src[j]);
  int4 v; __builtin_memcpy(&v, tmp, 16);
  ((int4*)X8)[idx] = v;
}

extern "C" __global__ void __launch_bounds__(TPB, 1)
lstm_mega(const float* __restrict__ Wih0, const float* __restrict__ Whh0,
          const float* __restrict__ bih0, const float* __restrict__ bhh0,
          const float* __restrict__ Wih1, const float* __restrict__ Whh1,
          const float* __restrict__ bih1, const float* __restrict__ bhh1,
          const unsigned short* __restrict__ X8, char* __restrict__ ws,
          float* __restrict__ out)
{
  extern __shared__ unsigned short Ws[];   // [32][KP]
  const int tid   = threadIdx.x;
  const int wg    = blockIdx.x;
  const int layer = (wg >= NL0);
  const int wgl   = layer ? wg - NL0 : wg;
  const int KP    = layer ? K1P : K0P;
  const int KD    = layer ? K1  : K0;
  const int dlen  = layer ? HD  : DIN;

  unsigned* flags = (unsigned*)(ws + WS_FLAGS);
  unsigned* gen   = (unsigned*)(ws + WS_GEN);
  const unsigned long long* H0r = (const unsigned long long*)(ws + WS_H0);
  const unsigned long long* H1r = (const unsigned long long*)(ws + WS_H1);
  unsigned short* H0w = (unsigned short*)(ws + WS_H0);
  unsigned short* H1w = (unsigned short*)(ws + WS_H1);
  const int4* X4 = (const int4*)X8;

  // ---- stage this WG's 32 gate-rows (8 cols x 4 gates) of its layer into LDS ----
  {
    const float* Wih = layer ? Wih1 : Wih0;
    const float* Whh = layer ? Whh1 : Whh0;
    for (int m = 0; m < 32; ++m){
      int gr = (m & 3)*HD + wgl*8 + (m >> 2);      // gate-major global row
      const float* ar = Wih + (size_t)gr*dlen;
      const float* br = Whh + (size_t)gr*HD;
      unsigned short* row = Ws + m*KP;
      for (int k = tid; k < KD; k += TPB)
        row[k] = f2bf(k < dlen ? ar[k] : br[k - dlen]);
    }
  }
  __syncthreads();

  const int lane  = tid & 63;
  const int wv    = tid >> 6;
  const int q     = lane >> 4;       // k-quad (A/B frags); row-quad (C/D)
  const int nn    = lane & 15;       // A-row / B-batch / C-batch
  const int batch = wv*16 + nn;

  // per-thread biases: cols wgl*8 + rt*4 + q, gates 0..3
  float bias[2][4];
  {
    const float* bi = layer ? bih1 : bih0;
    const float* bh = layer ? bhh1 : bhh0;
    #pragma unroll
    for (int rt = 0; rt < 2; ++rt){
      int colr = wgl*8 + rt*4 + q;
      #pragma unroll
      for (int r = 0; r < 4; ++r)
        bias[rt][r] = bi[r*HD + colr] + bh[r*HD + colr];
    }
  }

  float cst[2] = {0.f, 0.f};
  float hv[2]  = {0.f, 0.f};

  // one LSTM step for this WG's 8 cols x 16 batches (per wave)
  auto do_step = [&](int t){
    f32x4 a00 = {0,0,0,0}, a01 = {0,0,0,0}, a10 = {0,0,0,0}, a11 = {0,0,0,0};
    if (!layer){
      const int4* xb = X4 + t*2048;
      const unsigned long long* hb = H0r + ((t+1)&1)*HBUF_U64;
      #pragma unroll
      for (int kb = 0; kb < 8; ++kb){          // x part (L2-cached)
        int4 braw = xb[(kb*4 + q)*64 + batch];
        bf16x8 b, a0, a1;
        __builtin_memcpy(&b, &braw, 16);
        __builtin_memcpy(&a0, &Ws[nn*K0P + kb*32 + q*8], 16);
        __builtin_memcpy(&a1, &Ws[(16+nn)*K0P + kb*32 + q*8], 16);
        if (kb & 1){ a01 = __builtin_amdgcn_mfma_f32_16x16x32_bf16(a0,b,a01,0,0,0);
                     a11 = __builtin_amdgcn_mfma_f32_16x16x32_bf16(a1,b,a11,0,0,0); }
        else       { a00 = __builtin_amdgcn_mfma_f32_16x16x32_bf16(a0,b,a00,0,0,0);
                     a10 = __builtin_amdgcn_mfma_f32_16x16x32_bf16(a1,b,a10,0,0,0); }
      }
      #pragma unroll 4
      for (int kb = 8; kb < 40; ++kb){         // h0 part (coherent IF reads)
        int e = (((kb-8)*4 + q)*64 + batch)*2;
        unsigned long long lo = ld64c(hb + e), hi = ld64c(hb + e + 1);
        unsigned long long pair[2] = {lo, hi};
        bf16x8 b, a0, a1;
        __builtin_memcpy(&b, pair, 16);
        __builtin_memcpy(&a0, &Ws[nn*K0P + kb*32 + q*8], 16);
        __builtin_memcpy(&a1, &Ws[(16+nn)*K0P + kb*32 + q*8], 16);
        if (kb & 1){ a01 = __builtin_amdgcn_mfma_f32_16x16x32_bf16(a0,b,a01,0,0,0);
                     a11 = __builtin_amdgcn_mfma_f32_16x16x32_bf16(a1,b,a11,0,0,0); }
        else       { a00 = __builtin_amdgcn_mfma_f32_16x16x32_bf16(a0,b,a00,0,0,0);
                     a10 = __builtin_amdgcn_mfma_f32_16x16x32_bf16(a1,b,a10,0,0,0); }
      }
    } else {
      const unsigned long long* yb = H0r + (t&1)*HBUF_U64;        // y0(t)
      const unsigned long long* hb = H1r + ((t+1)&1)*HBUF_U64;    // h1(t-1)
      #pragma unroll 4
      for (int kb = 0; kb < 64; ++kb){
        int plane = (kb < 32) ? (kb*4 + q) : ((kb-32)*4 + q);
        const unsigned long long* src = (kb < 32) ? yb : hb;
        int e = (plane*64 + batch)*2;
        unsigned long long lo = ld64c(src + e), hi = ld64c(src + e + 1);
        unsigned long long pair[2] = {lo, hi};
        bf16x8 b, a0, a1;
        __builtin_memcpy(&b, pair, 16);
        __builtin_memcpy(&a0, &Ws[nn*K1P + kb*32 + q*8], 16);
        __builtin_memcpy(&a1, &Ws[(16+nn)*K1P + kb*32 + q*8], 16);
        if (kb & 1){ a01 = __builtin_amdgcn_mfma_f32_16x16x32_bf16(a0,b,a01,0,0,0);
                     a11 = __builtin_amdgcn_mfma_f32_16x16x32_bf16(a1,b,a11,0,0,0); }
        else       { a00 = __builtin_amdgcn_mfma_f32_16x16x32_bf16(a0,b,a00,0,0,0);
                     a10 = __builtin_amdgcn_mfma_f32_16x16x32_bf16(a1,b,a10,0,0,0); }
      }
    }
    f32x4 s0 = a00 + a01, s1 = a10 + a11;
    #pragma unroll
    for (int rt = 0; rt < 2; ++rt){
      f32x4 s = rt ? s1 : s0;
      float ii = sigmf(s[0] + bias[rt][0]);
      float ff = sigmf(s[1] + bias[rt][1]);
      float gg = tanhf_fast(s[2] + bias[rt][2]);
      float oo = sigmf(s[3] + bias[rt][3]);
      cst[rt] = ff*cst[rt] + ii*gg;
      hv[rt]  = oo*tanhf_fast(cst[rt]);
      unsigned short* dst = (layer ? H1w : H0w) + (t&1)*HBUF_US
                          + (wgl*64 + batch)*8 + (rt*4 + q);
      st16c(dst, f2bf(hv[rt]));
    }
  };

  if (!layer){
    for (int s = 0; s < T_STEPS; ++s){
      do_step(s);
      gridbar(flags, gen, (unsigned)(s+1), wg, tid);
    }
  } else {
    for (int s = 0; s < T_STEPS; ++s){
      if (s > 0) do_step(s-1);
      gridbar(flags, gen, (unsigned)(s+1), wg, tid);
    }
    do_step(T_STEPS-1);   // final layer1 step, no barrier needed after
  }

  // out = [h0 | h1 | c0 | c1], each [B=64, H=1024] fp32
  {
    int col0 = wgl*8 + q;           // rt=0 col; rt=1 is col0+4
    int base = layer ? 65536 : 0;   // h blob offset
    out[base          + batch*HD + col0    ] = hv[0];
    out[base          + batch*HD + col0 + 4] = hv[1];
    out[base + 131072 + batch*HD + col0    ] = cst[0];
    out[base + 131072 + batch*HD + col0 + 4] = cst[1];
  }
}

extern "C" void kernel_launch(void* const* d_in, const int* in_sizes, int n_in,
                              void* d_out, int out_size, void* d_ws, size_t ws_size,
                              hipStream_t stream)
{
  const float* x    = (const float*)d_in[0];
  const float* Wih0 = (const float*)d_in[1];
  const float* Whh0 = (const float*)d_in[2];
  const float* bih0 = (const float*)d_in[3];
  const float* bhh0 = (const float*)d_in[4];
  const float* Wih1 = (const float*)d_in[5];
  const float* Whh1 = (const float*)d_in[6];
  const float* bih1 = (const float*)d_in[7];
  const float* bhh1 = (const float*)d_in[8];
  float* out = (float*)d_out;

  char* ws = (char*)d_ws;
  unsigned short* X8 = (unsigned short*)(ws + WS_X8);

  // zero flags/gen + both h double-buffers (h(-1) = c(-1) = 0)
  hipMemsetAsync(d_ws, 0, WS_ZERO, stream);
  xpose_kernel<<<8192, 256, 0, stream>>>(x, X8);

  hipFuncSetAttribute((const void*)lstm_mega,
                      hipFuncAttributeMaxDynamicSharedMemorySize, SMEM_BYTES);

  const unsigned short* X8c = X8;
  void* args[] = {(void*)&Wih0,(void*)&Whh0,(void*)&bih0,(void*)&bhh0,
                  (void*)&Wih1,(void*)&Whh1,(void*)&bih1,(void*)&bhh1,
                  (void*)&X8c,(void*)&ws,(void*)&out};
  hipLaunchCooperativeKernel((void*)lstm_mega, dim3(NWG), dim3(TPB),
                             args, SMEM_BYTES, stream);
}

// Round 4
// 7773.584 us; speedup vs baseline: 13.9899x; 1.6330x over previous
//
#include <hip/hip_runtime.h>

#define NWG     256
#define TPB     256
#define NL0     128          // WGs [0,128) = layer0, [128,256) = layer1
#define T_STEPS 1024
#define HD      1024
#define DIN     256
#define K0      1280         // DIN + HD
#define K1      2048         // HD + HD
#define K0P     1288         // padded LDS row stride (shorts)
#define K1P     2056
#define SMEM_BYTES (32*K1P*2)   // 131,584 B (layer1 worst case)

// workspace layout (bytes)
#define WS_FLAGS 0                       // 256 x 64B
#define WS_GEN   16384                   // 16 x 64B
#define WS_H0    32768                   // 2 x 131072
#define WS_H1    (32768 + 262144)
#define WS_ZERO  (32768 + 524288)        // memset [0, WS_ZERO)
#define WS_X8    1048576                 // 1024*32*64*8 bf16 = 33.5 MB
#define HBUF_US  65536                   // ushorts per h buffer
#define HBUF_U64 16384                   // u64 per h buffer
#define NGEN     16

typedef float  f32x4  __attribute__((ext_vector_type(4)));
typedef __bf16 bf16x8 __attribute__((ext_vector_type(8)));
typedef unsigned long long u64;

__device__ __forceinline__ unsigned short f2bf(float f){
  union { float f; unsigned u; } a; a.f = f;
  unsigned u = a.u;
  u += 0x7fffu + ((u >> 16) & 1u);   // RNE
  return (unsigned short)(u >> 16);
}
__device__ __forceinline__ float sigmf(float x){ return 1.0f/(1.0f + __expf(-x)); }
__device__ __forceinline__ float tanhf_fast(float x){ return 2.0f*sigmf(2.0f*x) - 1.0f; }

// coherent (IF-level, cross-XCD) accessors — per-access, no L2 invalidation
__device__ __forceinline__ u64 ld64c(const u64* p){
  return __hip_atomic_load(p, __ATOMIC_RELAXED, __HIP_MEMORY_SCOPE_AGENT);
}
__device__ __forceinline__ void st16c(unsigned short* p, unsigned short v){
  __hip_atomic_store(p, v, __ATOMIC_RELAXED, __HIP_MEMORY_SCOPE_AGENT);
}
__device__ __forceinline__ unsigned ldflag(const unsigned* p){
  return __hip_atomic_load(p, __ATOMIC_RELAXED, __HIP_MEMORY_SCOPE_AGENT);
}
__device__ __forceinline__ void stflag(unsigned* p, unsigned v){
  __hip_atomic_store(p, v, __ATOMIC_RELAXED, __HIP_MEMORY_SCOPE_AGENT);
}

// round-2 proven leader barrier: WG0 collects flags, fans out via NGEN gen lines.
__device__ __forceinline__ void gridbar(unsigned* flags, unsigned* gen,
                                        unsigned ep, int wg, int tid){
  asm volatile("s_waitcnt vmcnt(0)" ::: "memory");  // my h-stores are at IF
  __syncthreads();                                  // all waves of this WG drained
  if (wg == 0){
    if (tid > 0){
      while (ldflag(&flags[tid*16]) < ep) __builtin_amdgcn_s_sleep(4);
    }
    __syncthreads();
    if (tid < NGEN) stflag(&gen[tid*16], ep);
    __syncthreads();
  } else {
    if (tid == 0){
      stflag(&flags[wg*16], ep);
      while (ldflag(&gen[(wg & (NGEN-1))*16]) < ep) __builtin_amdgcn_s_sleep(4);
    }
    __syncthreads();
  }
}

// x [B,T,D] fp32 -> X8 bf16 in [T][D/8][B][8]
__global__ void xpose_kernel(const float* __restrict__ x, unsigned short* __restrict__ X8){
  int idx   = blockIdx.x*256 + threadIdx.x;
  int t     = idx >> 11;
  int rem   = idx & 2047;
  int plane = rem >> 6;
  int b     = rem & 63;
  const float* src = x + ((size_t)b << 18) + (t << 8) + (plane << 3);
  unsigned short tmp[8];
  #pragma unroll
  for (int j = 0; j < 8; ++j) tmp[j] = f2bf(src[j]);
  int4 v; __builtin_memcpy(&v, tmp, 16);
  ((int4*)X8)[idx] = v;
}

extern "C" __global__ void __launch_bounds__(TPB, 1)
lstm_mega(const float* __restrict__ Wih0, const float* __restrict__ Whh0,
          const float* __restrict__ bih0, const float* __restrict__ bhh0,
          const float* __restrict__ Wih1, const float* __restrict__ Whh1,
          const float* __restrict__ bih1, const float* __restrict__ bhh1,
          const unsigned short* __restrict__ X8, char* __restrict__ ws,
          float* __restrict__ out)
{
  extern __shared__ unsigned short Ws[];   // [32][KP]
  const int tid   = threadIdx.x;
  const int wg    = blockIdx.x;
  const int layer = (wg >= NL0);
  const int wgl   = layer ? wg - NL0 : wg;
  const int KD    = layer ? K1  : K0;
  const int dlen  = layer ? HD  : DIN;
  const int KP    = layer ? K1P : K0P;

  unsigned* flags = (unsigned*)(ws + WS_FLAGS);
  unsigned* gen   = (unsigned*)(ws + WS_GEN);
  const u64* H0r  = (const u64*)(ws + WS_H0);
  const u64* H1r  = (const u64*)(ws + WS_H1);
  unsigned short* H0w = (unsigned short*)(ws + WS_H0);
  unsigned short* H1w = (unsigned short*)(ws + WS_H1);
  const int4* X4 = (const int4*)X8;

  // ---- stage this WG's 32 gate-rows (8 cols x 4 gates) into LDS (bf16) ----
  {
    const float* Wih = layer ? Wih1 : Wih0;
    const float* Whh = layer ? Whh1 : Whh0;
    for (int m = 0; m < 32; ++m){
      int gr = (m & 3)*HD + wgl*8 + (m >> 2);      // gate-major global row
      const float* ar = Wih + (size_t)gr*dlen;
      const float* br = Whh + (size_t)gr*HD;
      unsigned short* row = Ws + m*KP;
      for (int k = tid; k < KD; k += TPB)
        row[k] = f2bf(k < dlen ? ar[k] : br[k - dlen]);
    }
  }
  __syncthreads();

  const int lane  = tid & 63;
  const int wv    = tid >> 6;
  const int q     = lane >> 4;       // k-quad (A/B frags); row-quad (C/D)
  const int nn    = lane & 15;       // A-row / B-batch / C-batch
  const int batch = wv*16 + nn;

  float bias[2][4];
  {
    const float* bi = layer ? bih1 : bih0;
    const float* bh = layer ? bhh1 : bhh0;
    #pragma unroll
    for (int rt = 0; rt < 2; ++rt){
      int colr = wgl*8 + rt*4 + q;
      #pragma unroll
      for (int r = 0; r < 4; ++r)
        bias[rt][r] = bi[r*HD + colr] + bh[r*HD + colr];
    }
  }

  float cst[2] = {0.f, 0.f};
  float hv[2]  = {0.f, 0.f};

  auto do_step = [&](int t){
    f32x4 a00 = {0,0,0,0}, a01 = {0,0,0,0}, a10 = {0,0,0,0}, a11 = {0,0,0,0};

    auto MM = [&](int kb, bf16x8 b){
      bf16x8 a0, a1;
      __builtin_memcpy(&a0, &Ws[nn*KP + kb*32 + q*8], 16);
      __builtin_memcpy(&a1, &Ws[(16+nn)*KP + kb*32 + q*8], 16);
      if (kb & 1){ a01 = __builtin_amdgcn_mfma_f32_16x16x32_bf16(a0,b,a01,0,0,0);
                   a11 = __builtin_amdgcn_mfma_f32_16x16x32_bf16(a1,b,a11,0,0,0); }
      else       { a00 = __builtin_amdgcn_mfma_f32_16x16x32_bf16(a0,b,a00,0,0,0);
                   a10 = __builtin_amdgcn_mfma_f32_16x16x32_bf16(a1,b,a10,0,0,0); }
    };

    if (!layer){
      // ---- layer 0: gates = W0 @ [x_t ; h0(t-1)] ----
      const int4* xb = X4 + t*2048;
      const u64* hb  = H0r + ((t+1)&1)*HBUF_U64;

      int4 xr[8];
      #pragma unroll
      for (int kb = 0; kb < 8; ++kb)            // x part: L2-cached, issue first
        xr[kb] = xb[(kb*4 + q)*64 + batch];

      u64 B[3][16];                             // 8 kb-planes per chunk, depth-3
      auto LD = [&](int c){                     // chunk c: h-planes c*8 .. c*8+7
        u64* d = B[c % 3];
        #pragma unroll
        for (int i = 0; i < 8; ++i){
          int e = (((c*8 + i)*4 + q)*64 + batch)*2;
          d[2*i]   = ld64c(hb + e);
          d[2*i+1] = ld64c(hb + e + 1);
        }
      };
      LD(0); LD(1);
      #pragma unroll
      for (int kb = 0; kb < 8; ++kb){           // consume x while h chunks fly
        bf16x8 b; __builtin_memcpy(&b, &xr[kb], 16);
        MM(kb, b);
      }
      LD(2);
      #pragma unroll
      for (int c = 0; c < 4; ++c){
        u64* d = B[c % 3];
        #pragma unroll
        for (int i = 0; i < 8; ++i){
          u64 pair[2] = {d[2*i], d[2*i+1]};
          bf16x8 b; __builtin_memcpy(&b, pair, 16);
          MM(8 + c*8 + i, b);
        }
        if (c + 3 < 4) LD(c + 3);
      }
    } else {
      // ---- layer 1: gates = W1 @ [y0(t) ; h1(t-1)] ----
      const u64* yb = H0r + (t&1)*HBUF_U64;
      const u64* hb = H1r + ((t+1)&1)*HBUF_U64;

      u64 B[3][16];                             // 8 chunks of 8 kb, depth-3
      auto LD = [&](int c){                     // c<4 from yb, else from hb
        const u64* src = (c < 4) ? yb : hb;
        int p0 = (c & 3)*8;
        u64* d = B[c % 3];
        #pragma unroll
        for (int i = 0; i < 8; ++i){
          int e = (((p0 + i)*4 + q)*64 + batch)*2;
          d[2*i]   = ld64c(src + e);
          d[2*i+1] = ld64c(src + e + 1);
        }
      };
      LD(0); LD(1); LD(2);
      #pragma unroll
      for (int c = 0; c < 8; ++c){
        u64* d = B[c % 3];
        #pragma unroll
        for (int i = 0; i < 8; ++i){
          u64 pair[2] = {d[2*i], d[2*i+1]};
          bf16x8 b; __builtin_memcpy(&b, pair, 16);
          MM(c*8 + i, b);
        }
        if (c + 3 < 8) LD(c + 3);
      }
    }

    f32x4 s0 = a00 + a01, s1 = a10 + a11;
    #pragma unroll
    for (int rt = 0; rt < 2; ++rt){
      f32x4 s = rt ? s1 : s0;
      float ii = sigmf(s[0] + bias[rt][0]);
      float ff = sigmf(s[1] + bias[rt][1]);
      float gg = tanhf_fast(s[2] + bias[rt][2]);
      float oo = sigmf(s[3] + bias[rt][3]);
      cst[rt] = ff*cst[rt] + ii*gg;
      hv[rt]  = oo*tanhf_fast(cst[rt]);
      unsigned short* dst = (layer ? H1w : H0w) + (t&1)*HBUF_US
                          + (wgl*64 + batch)*8 + (rt*4 + q);
      st16c(dst, f2bf(hv[rt]));
    }
  };

  if (!layer){
    for (int s = 0; s < T_STEPS; ++s){
      do_step(s);
      gridbar(flags, gen, (unsigned)(s+1), wg, tid);
    }
  } else {
    for (int s = 0; s < T_STEPS; ++s){
      if (s > 0) do_step(s-1);
      gridbar(flags, gen, (unsigned)(s+1), wg, tid);
    }
    do_step(T_STEPS-1);
  }

  // out = [h0 | h1 | c0 | c1], each [B=64, H=1024] fp32
  {
    int col0 = wgl*8 + q;
    int base = layer ? 65536 : 0;
    out[base          + batch*HD + col0    ] = hv[0];
    out[base          + batch*HD + col0 + 4] = hv[1];
    out[base + 131072 + batch*HD + col0    ] = cst[0];
    out[base + 131072 + batch*HD + col0 + 4] = cst[1];
  }
}

extern "C" void kernel_launch(void* const* d_in, const int* in_sizes, int n_in,
                              void* d_out, int out_size, void* d_ws, size_t ws_size,
                              hipStream_t stream)
{
  const float* x    = (const float*)d_in[0];
  const float* Wih0 = (const float*)d_in[1];
  const float* Whh0 = (const float*)d_in[2];
  const float* bih0 = (const float*)d_in[3];
  const float* bhh0 = (const float*)d_in[4];
  const float* Wih1 = (const float*)d_in[5];
  const float* Whh1 = (const float*)d_in[6];
  const float* bih1 = (const float*)d_in[7];
  const float* bhh1 = (const float*)d_in[8];
  float* out = (float*)d_out;

  char* ws = (char*)d_ws;
  unsigned short* X8 = (unsigned short*)(ws + WS_X8);

  // zero flags/gen + both h double-buffers (h(-1) = 0)
  hipMemsetAsync(d_ws, 0, WS_ZERO, stream);
  xpose_kernel<<<8192, 256, 0, stream>>>(x, X8);

  hipFuncSetAttribute((const void*)lstm_mega,
                      hipFuncAttributeMaxDynamicSharedMemorySize, SMEM_BYTES);

  const unsigned short* X8c = X8;
  void* args[] = {(void*)&Wih0,(void*)&Whh0,(void*)&bih0,(void*)&bhh0,
                  (void*)&Wih1,(void*)&Whh1,(void*)&bih1,(void*)&bhh1,
                  (void*)&X8c,(void*)&ws,(void*)&out};
  hipError_t err = hipLaunchCooperativeKernel((void*)lstm_mega, dim3(NWG), dim3(TPB),
                                              args, SMEM_BYTES, stream);
  if (err != hipSuccess){
    // Fallback: plain launch. 256 WGs x 131KB LDS x <=512 VGPR => 1 WG/CU,
    // grid == CU count, all WGs co-resident by capacity.
    lstm_mega<<<dim3(NWG), dim3(TPB), SMEM_BYTES, stream>>>(
        Wih0, Whh0, bih0, bhh0, Wih1, Whh1, bih1, bhh1, X8c, ws, out);
  }
}